// Round 5
// baseline (66.313 us; speedup 1.0000x reference)
//
#include <hip/hip_runtime.h>

// Problem constants (from reference setup_inputs)
static constexpr int kA = 128;   // atoms
static constexpr int kN = 64;    // neighbors
static constexpr int kG = 16;    // grid size per axis
static constexpr int kC = 10;    // channels = 5 types x 2 grid lengths
static constexpr int kP = 17;    // padded tick stride (16+1): odd stride ->
                                 // staging ds_writes cover all 32 banks

// out[b=0][a][c][x][y][z], c = type_idx*2 + length_idx
// Per channel (Z, L):
//   out = sum_{n: Z_n == Z} exp(coeff*||g - d_n||^2) + (N - cnt_Z) * exp(coeff*|g|^2)
// (reference masks d, not the exp). Separable: exp = ex*ey*ez.
//
// Round-5: kill the 32-way LDS write conflict in table staging.
//  R4 wrote s_tab[(ax*64+n)*16+i] with (n=t/3,ax=t%3): for fixed i a wave's
//  64 lanes land in exactly 2 banks (16k+i mod 32, k parity) -> 32-way
//  conflict x 16 writes/thread x 3 waves. Fix: pad tick dim to 17 and remap
//  staging to (n=t&63, ax=t>>6) -> per-lane stride 17 words (odd) covers all
//  32 banks, conflict-free. Reads stay conflict-free (broadcast patterns).

__global__ __launch_bounds__(256) void voxel_kernel(
    const float* __restrict__ dvec,   // (1, A, N, 3) fp32
    const float* __restrict__ sigma,  // (1,) fp32
    const int*   __restrict__ zn,     // (A, N) int32
    float*       __restrict__ out)    // (1, A, 10, G, G, G) fp32
{
    const int blk = blockIdx.x;          // a*10 + c,  c = ch*2 + li
    const int a   = blk / 10;
    const int c   = blk - a * 10;
    const int ch  = c >> 1;
    const int li  = c & 1;

    const int Ztab[5] = {1, 6, 7, 8, 16};
    const int Ztarget = Ztab[ch];

    const float Lg   = li ? 12.0f : 8.0f;
    const float step = Lg * (1.0f / 15.0f);
    const float t0   = -0.5f * Lg;
    const float sg   = sigma[0];
    const float coeff = -0.5f / (sg * sg);

    const int t = threadIdx.x;           // 0..255

    __shared__ float s_tab[3 * kN * kP]; // [axis][n][tick(17)], ~12.75 KB
    __shared__ float s_e0[kG];           // exp(coeff*tick^2)

    // --- Stage separable tables. Thread t<192: n = t&63, ax = t>>6.
    //     dvec layout (N,3): element (n,ax) at n*3+ax (stride-3 read, one
    //     768 B segment per wave). Writes: per-lane base 17*n -> stride 17
    //     words across the wave -> all 32 banks, conflict-free.
    if (t < 192) {
        const int   n  = t & 63;
        const int   ax = t >> 6;
        const float d  = dvec[(size_t)a * (kN * 3) + n * 3 + ax];
        float* dst = &s_tab[(ax * kN + n) * kP];
#pragma unroll
        for (int i = 0; i < kG; ++i) {
            const float r = (t0 + i * step) - d;
            dst[i] = __expf(coeff * r * r);
        }
    } else if (t < 192 + kG) {
        const int i = t - 192;
        const float r = t0 + i * step;
        s_e0[i] = __expf(coeff * r * r);
    }

    // --- Classification: per-wave ballot; mask identical in every wave.
    const int lane = t & 63;
    const int Zl   = zn[a * kN + lane];
    unsigned long long mask = __ballot(Zl == Ztarget);
    const int cnt = __popcll(mask);

    __syncthreads();

    // Ownership mapping: float4 #(t + 256q) = (x = t>>6 + 4q, y = (t>>2)&15,
    // z = 4*(t&3)..+3) -> stores are contiguous 1 KB per wave-instruction.
    const int y  = (t >> 2) & 15;
    const int zq = (t & 3) * 4;
    const int xb = t >> 6;               // wave id; x_i = xb + 4i

    const float* s_ex = &s_tab[0 * kN * kP];
    const float* s_ey = &s_tab[1 * kN * kP];
    const float* s_ez = &s_tab[2 * kN * kP];

    // --- Origin-centered term via the s_e0 table.
    float acc[4][4];
    {
        const float w  = (float)(kN - cnt) * s_e0[y];
        float ez0[4];
#pragma unroll
        for (int j = 0; j < 4; ++j) ez0[j] = s_e0[zq + j];
#pragma unroll
        for (int i = 0; i < 4; ++i) {
            const float wx = w * s_e0[xb + 4 * i];
#pragma unroll
            for (int j = 0; j < 4; ++j)
                acc[i][j] = wx * ez0[j];
        }
    }

    // --- Matched neighbors: iterate set bits of the SGPR mask.
    //     Reads: s_ex uniform (64-lane broadcast), s_ey 16 consecutive addrs
    //     (16 banks, 4-lane broadcast), s_ez 4 addrs (16-lane broadcast).
    while (mask) {
        const int n = (int)__builtin_ctzll(mask);   // wave-uniform
        mask &= mask - 1ull;
        const float eyn = s_ey[n * kP + y];
        float ezn[4];
#pragma unroll
        for (int j = 0; j < 4; ++j) ezn[j] = s_ez[n * kP + zq + j];
#pragma unroll
        for (int i = 0; i < 4; ++i) {
            const float p = s_ex[n * kP + xb + 4 * i] * eyn;
#pragma unroll
            for (int j = 0; j < 4; ++j)
                acc[i][j] = fmaf(p, ezn[j], acc[i][j]);
        }
    }

    // --- Fully-coalesced store: per instruction q, lane l writes float4
    //     #(wave*64 + l + 256q) — contiguous 1 KB per wave, full lines.
    float4* o = (float4*)(out + ((size_t)a * kC + c) * (kG * kG * kG));
#pragma unroll
    for (int q = 0; q < 4; ++q)
        o[t + 256 * q] = make_float4(acc[q][0], acc[q][1], acc[q][2], acc[q][3]);
}

extern "C" void kernel_launch(void* const* d_in, const int* in_sizes, int n_in,
                              void* d_out, int out_size, void* d_ws, size_t ws_size,
                              hipStream_t stream) {
    const float* dvec  = (const float*)d_in[0];   // distance_vector (1,128,64,3) fp32
    const float* sigma = (const float*)d_in[1];   // sigma (1,) fp32
    const int*   zn    = (const int*)d_in[2];     // atomic_numbers (128,64) int32
    float* out = (float*)d_out;                   // (1,128,10,16,16,16) fp32

    voxel_kernel<<<dim3(kA * kC), dim3(256), 0, stream>>>(dvec, sigma, zn, out);
}